// Round 5
// baseline (797.491 us; speedup 1.0000x reference)
//
#include <hip/hip_runtime.h>

#define N_TOK 100000

typedef __attribute__((ext_vector_type(4))) float floatx4;

// ---------------- kernel 1: sims[b,n] = -dot(q,keys)/sqrt(128); fused sum(exp(sims)) per b
__global__ __launch_bounds__(256) void k_sims(const float* __restrict__ q,
                                              const float* __restrict__ keys,
                                              float* __restrict__ sims,
                                              float* __restrict__ scal) {
  __shared__ float qs[128];
  __shared__ float red[4];
  const int b = blockIdx.y;
  const int tid = threadIdx.x;
  if (tid < 128) qs[tid] = q[b * 128 + tid];
  __syncthreads();
  const int n0 = blockIdx.x * 1024 + tid * 4;
  float part = 0.f;
  if (n0 < N_TOK) {
    const float* kb = keys + (size_t)b * 128 * N_TOK + n0;
    float ax = 0.f, ay = 0.f, az = 0.f, aw = 0.f;
#pragma unroll 8
    for (int d = 0; d < 128; ++d) {
      float4 kv = *(const float4*)(kb + (size_t)d * N_TOK);
      float qd = qs[d];
      ax = fmaf(qd, kv.x, ax); ay = fmaf(qd, kv.y, ay);
      az = fmaf(qd, kv.z, az); aw = fmaf(qd, kv.w, aw);
    }
    const float sc = -0.08838834764831843f;  // -1/sqrt(128)
    float4 s4; s4.x = ax * sc; s4.y = ay * sc; s4.z = az * sc; s4.w = aw * sc;
    *(float4*)(sims + (size_t)b * N_TOK + n0) = s4;
    part = __expf(s4.x) + __expf(s4.y) + __expf(s4.z) + __expf(s4.w);
  }
#pragma unroll
  for (int off = 32; off > 0; off >>= 1) part += __shfl_down(part, off);
  if ((tid & 63) == 0) red[tid >> 6] = part;
  __syncthreads();
  if (tid == 0) atomicAdd(&scal[b * 32], red[0] + red[1] + red[2] + red[3]);
}

// ---------------- kernel 2: T_c[f] = sum_n eps(n)^c * V[f,n], c=0,1,2, where
// eps(n) = expm1(10 * exp(sims[n]) / S0)  (eps <= ~9e-3). Also P1=sum eps, P2=sum eps^2.
// Pure streaming pass over values[] at HBM BW; no MFMA needed.
#define TCH 512
#define TGX 196   // ceil(100000/512)
__global__ __launch_bounds__(256) void k_T(const float* __restrict__ sims,
                                           const float* __restrict__ values,
                                           float* __restrict__ scal,
                                           float* __restrict__ Tacc) {
  __shared__ __align__(16) float e1s[TCH];
  __shared__ __align__(16) float e2s[TCH];
  __shared__ float redp[2][4];
  const int b = blockIdx.y;
  const int tid = threadIdx.x;
  const float r0 = 1.f / scal[b * 32];
  const int n0 = blockIdx.x * TCH;

  // prologue: eps, eps^2 for this chunk's TCH tokens; accumulate P1,P2 partials
  float p1 = 0.f, p2 = 0.f;
  {
    int n = n0 + tid * 2;
    float ea = 0.f, eb = 0.f;
    if (n < N_TOK) {  // N even: n<N implies n+1<N
      float2 s2 = *(const float2*)(sims + (size_t)b * N_TOK + n);
      float xa = 10.f * __expf(s2.x) * r0;
      float xb = 10.f * __expf(s2.y) * r0;
      // expm1 to f32 precision for x <= ~9e-3
      ea = xa * fmaf(xa, fmaf(xa, fmaf(xa, 1.f / 24.f, 1.f / 6.f), 0.5f), 1.f);
      eb = xb * fmaf(xb, fmaf(xb, fmaf(xb, 1.f / 24.f, 1.f / 6.f), 0.5f), 1.f);
      p1 = ea + eb; p2 = ea * ea + eb * eb;
    }
    e1s[tid * 2] = ea;     e1s[tid * 2 + 1] = eb;
    e2s[tid * 2] = ea * ea; e2s[tid * 2 + 1] = eb * eb;
  }
#pragma unroll
  for (int off = 32; off > 0; off >>= 1) { p1 += __shfl_down(p1, off); p2 += __shfl_down(p2, off); }
  if ((tid & 63) == 0) { redp[0][tid >> 6] = p1; redp[1][tid >> 6] = p2; }
  __syncthreads();
  if (tid == 0) {
    atomicAdd(&scal[b * 32 + 1], redp[0][0] + redp[0][1] + redp[0][2] + redp[0][3]);
    atomicAdd(&scal[b * 32 + 2], redp[1][0] + redp[1][1] + redp[1][2] + redp[1][3]);
  }

  // main: 4 waves x 32 f-rows; per row stream TCH n, 3 weighted sums
  const int lane = tid & 63, wv = tid >> 6;
  const float* vp = values + ((size_t)b * 128 + wv * 32) * N_TOK + n0 + lane * 4;
#pragma unroll 4
  for (int j = 0; j < 32; ++j) {
    int f = wv * 32 + j;
    float t0 = 0.f, t1 = 0.f, t2 = 0.f;
#pragma unroll
    for (int it = 0; it < TCH / 256; ++it) {
      int nn = n0 + it * 256 + lane * 4;
      if (nn < N_TOK) {
        float4 v = *(const float4*)(vp + it * 256);
        int li = it * 256 + lane * 4;
        float4 e1 = *(const float4*)&e1s[li];
        float4 e2 = *(const float4*)&e2s[li];
        t0 += (v.x + v.y) + (v.z + v.w);
        t1 = fmaf(e1.x, v.x, fmaf(e1.y, v.y, fmaf(e1.z, v.z, fmaf(e1.w, v.w, t1))));
        t2 = fmaf(e2.x, v.x, fmaf(e2.y, v.y, fmaf(e2.z, v.z, fmaf(e2.w, v.w, t2))));
      }
    }
#pragma unroll
    for (int off = 32; off > 0; off >>= 1) {
      t0 += __shfl_down(t0, off); t1 += __shfl_down(t1, off); t2 += __shfl_down(t2, off);
    }
    if (lane == 0) {
      atomicAdd(&Tacc[(b * 3 + 0) * 128 + f], t0);
      atomicAdd(&Tacc[(b * 3 + 1) * 128 + f], t1);
      atomicAdd(&Tacc[(b * 3 + 2) * 128 + f], t2);
    }
    vp += N_TOK;
  }
}

// ---------------- kernel 3: scalar polynomial recurrence + combine.
// E_k(eps) tracked as degree-2 poly e0+e1*eps+e2*eps^2 (exact to ~1e-10 over eps range).
// S_k = N*e0 + e1*P1 + e2*P2 ; w_k-poly c = R_k * e ; E <- E*(1 - 10w + 45w^2) trunc deg2.
// out[b,k,f] = c0*T0[f] + c1*T1[f] + c2*T2[f]  (full overwrite of d_out).
__global__ __launch_bounds__(256) void k_comb(const float* __restrict__ Tacc,
                                              const float* __restrict__ scal,
                                              float* __restrict__ out) {
  int i = blockIdx.x * 256 + threadIdx.x;
  if (i >= 16384) return;
  int b = i >> 11, k = (i >> 7) & 15, f = i & 127;
  float P1 = scal[b * 32 + 1], P2 = scal[b * 32 + 2];
  float e0 = 1.f, e1 = 1.f, e2 = 0.f;
  float c0 = 0.f, c1 = 0.f, c2 = 0.f;
  for (int kk = 0; kk <= k; ++kk) {
    float S = fmaf(e0, (float)N_TOK, fmaf(e1, P1, e2 * P2));
    float R = 1.f / S;
    c0 = R * e0; c1 = R * e1; c2 = R * e2;
    // q = 1 - 10u + 45u^2, u = (c0,c1,c2), truncated to degree 2
    float q0 = fmaf(45.f * c0, c0, fmaf(-10.f, c0, 1.f));
    float q1 = fmaf(90.f * c0, c1, -10.f * c1);
    float q2 = fmaf(45.f, fmaf(2.f * c0, c2, c1 * c1), -10.f * c2);
    float ne0 = e0 * q0;
    float ne1 = fmaf(e0, q1, e1 * q0);
    float ne2 = fmaf(e0, q2, fmaf(e1, q1, e2 * q0));
    e0 = ne0; e1 = ne1; e2 = ne2;
  }
  out[i] = fmaf(c0, Tacc[(b * 3 + 0) * 128 + f],
           fmaf(c1, Tacc[(b * 3 + 1) * 128 + f],
                c2 * Tacc[(b * 3 + 2) * 128 + f]));
}

extern "C" void kernel_launch(void* const* d_in, const int* in_sizes, int n_in,
                              void* d_out, int out_size, void* d_ws, size_t ws_size,
                              hipStream_t stream) {
  const float* q      = (const float*)d_in[0];
  const float* keys   = (const float*)d_in[1];
  const float* values = (const float*)d_in[2];
  float* Tacc = (float*)d_ws;            // 8 b x 3 c x 128 f = 3072 f32
  float* scal = Tacc + 3072;             // 8 batches x 32 scalar slots
  float* sims = scal + 256;              // 800000 f32
  (void)hipMemsetAsync(d_ws, 0, (3072 + 256) * sizeof(float), stream);
  dim3 g1(98, 8);
  k_sims<<<g1, 256, 0, stream>>>(q, keys, sims, scal);
  dim3 g2(TGX, 8);
  k_T<<<g2, 256, 0, stream>>>(sims, values, scal, Tacc);
  k_comb<<<64, 256, 0, stream>>>(Tacc, scal, (float*)d_out);
}